// Round 1
// baseline (350.063 us; speedup 1.0000x reference)
//
#include <hip/hip_runtime.h>
#include <cstdint>

typedef short bf8 __attribute__((ext_vector_type(8)));
typedef float f4 __attribute__((ext_vector_type(4)));

#define SEQ 2048
#define DIM 512
#define NMAT (512*512)
#define SCQ 0.04419417382415922f

__device__ inline unsigned short f2bf(float f){
    unsigned int u = __builtin_bit_cast(unsigned int, f);
    u = (u + 0x7FFFu + ((u >> 16) & 1u)) >> 16;
    return (unsigned short)u;
}

__device__ __forceinline__ void glds16(const unsigned short* gsrc, const unsigned short* ldst){
    __builtin_amdgcn_global_load_lds(
        (const __attribute__((address_space(1))) unsigned int*)gsrc,
        (__attribute__((address_space(3))) unsigned int*)ldst, 16, 0, 0);
}

// ---------------- kernel 0: W (f32 [k][n]) -> Wt (bf16 [n][k]) ----------------
__global__ void prep_w(const float* __restrict__ Wv, const float* __restrict__ Wk,
                       const float* __restrict__ Wq, unsigned short* __restrict__ Wt)
{
    const int m = blockIdx.y;
    const float* W = (m == 0) ? Wv : ((m == 1) ? Wk : Wq);
    const int o = blockIdx.x * 256 + threadIdx.x;
    const int n = o >> 9;
    const int k = o & 511;
    Wt[m * NMAT + o] = f2bf(W[k * 512 + n]);
}

// ---------------- kernel 1: fused 3x GEMM (+LN / +transpose epilogue) ----------------
__global__ __launch_bounds__(512, 1) void gemm3(
    const float* __restrict__ vals, const float* __restrict__ keys, const float* __restrict__ ques,
    const unsigned short* __restrict__ Wt,
    const float* __restrict__ kg, const float* __restrict__ kbe,
    const float* __restrict__ qg, const float* __restrict__ qbe,
    unsigned short* __restrict__ vt, unsigned short* __restrict__ kbuf, unsigned short* __restrict__ qbuf)
{
    __shared__ unsigned short a_lds[64 * DIM];   // 64 KB, XOR-swizzled rows
    float* red1    = (float*)a_lds;
    float* red2    = red1 + 512;
    float* stat_mu = red2 + 512;
    float* stat_rs = stat_mu + 64;

    const int tid = threadIdx.x;
    const int wv  = tid >> 6;
    const int l   = tid & 63;
    const int g   = l >> 4;
    const int lr  = l & 15;
    const int gid = blockIdx.x;
    const int m   = gid >> 8;            // 0=v, 1=k, 2=q
    const int r0  = (gid & 255) * 64;
    const float* X = (m == 0) ? vals : ((m == 1) ? keys : ques);
    const unsigned short* W = Wt + m * NMAT;

    {
        const int row = tid >> 3;
        const int cb  = (tid & 7) * 4;
        const float* xr = X + (size_t)(r0 + row) * DIM;
        #pragma unroll
        for (int i = 0; i < 16; ++i){
            const int col = cb + i * 32;
            const float4 v = *reinterpret_cast<const float4*>(xr + col);
            ushort4 h;
            h.x = f2bf(v.x); h.y = f2bf(v.y); h.z = f2bf(v.z); h.w = f2bf(v.w);
            const int byte = ((row * DIM + col) * 2) ^ ((row & 7) << 4);
            *reinterpret_cast<ushort4*>(reinterpret_cast<char*>(a_lds) + byte) = h;
        }
    }
    __syncthreads();

    f4 acc[4][4];
    #pragma unroll
    for (int i = 0; i < 4; ++i)
        #pragma unroll
        for (int j = 0; j < 4; ++j)
            acc[i][j] = (f4){0.f, 0.f, 0.f, 0.f};

    const int nb = wv * 64;
    #pragma unroll 4
    for (int ks = 0; ks < 16; ++ks){
        const int kof = ks * 32 + g * 8;
        bf8 af[4], bfr[4];
        #pragma unroll
        for (int rt = 0; rt < 4; ++rt){
            const int row = 16 * rt + lr;
            const int byte = ((row * DIM + kof) * 2) ^ ((row & 7) << 4);
            af[rt] = *reinterpret_cast<const bf8*>(reinterpret_cast<const char*>(a_lds) + byte);
        }
        #pragma unroll
        for (int ct = 0; ct < 4; ++ct)
            bfr[ct] = *reinterpret_cast<const bf8*>(W + (size_t)(nb + 16 * ct + lr) * DIM + kof);
        #pragma unroll
        for (int rt = 0; rt < 4; ++rt)
            #pragma unroll
            for (int ct = 0; ct < 4; ++ct)
                acc[rt][ct] = __builtin_amdgcn_mfma_f32_16x16x32_bf16(af[rt], bfr[ct], acc[rt][ct], 0, 0, 0);
    }

    if (m == 0){
        __syncthreads();
        #pragma unroll
        for (int rt = 0; rt < 4; ++rt)
            #pragma unroll
            for (int r = 0; r < 4; ++r){
                const int row = 16 * rt + g * 4 + r;
                #pragma unroll
                for (int ct = 0; ct < 4; ++ct){
                    const int d = nb + 16 * ct + lr;
                    const int byte = (d * 128 + row * 2) ^ ((d & 7) << 4);
                    *reinterpret_cast<unsigned short*>(reinterpret_cast<char*>(a_lds) + byte) = f2bf(acc[rt][ct][r]);
                }
            }
        __syncthreads();
        const int bb = r0 >> 11;
        const int s0 = r0 & 2047;
        #pragma unroll
        for (int pq = 0; pq < 4; ++pq){
            const int d  = pq * 128 + (tid >> 2);
            const int sc = (tid & 3) * 16;
            const int base = d * 128 + sc * 2;
            const int sw = (d & 7) << 4;
            const bf8 x0 = *reinterpret_cast<const bf8*>(reinterpret_cast<const char*>(a_lds) + (base ^ sw));
            const bf8 x1 = *reinterpret_cast<const bf8*>(reinterpret_cast<const char*>(a_lds) + ((base + 16) ^ sw));
            unsigned short* dst = vt + (size_t)(bb * 512 + d) * SEQ + s0 + sc;
            *reinterpret_cast<bf8*>(dst)     = x0;
            *reinterpret_cast<bf8*>(dst + 8) = x1;
        }
        return;
    }

    const float* gamma = (m == 1) ? kg  : qg;
    const float* beta  = (m == 1) ? kbe : qbe;
    const float scale  = (m == 1) ? 1.0f : SCQ;
    unsigned short* outp = (m == 1) ? kbuf : qbuf;

    __syncthreads();
    #pragma unroll
    for (int rt = 0; rt < 4; ++rt){
        #pragma unroll
        for (int r = 0; r < 4; ++r){
            float s1 = 0.f, s2 = 0.f;
            #pragma unroll
            for (int ct = 0; ct < 4; ++ct){ const float v = acc[rt][ct][r]; s1 += v; s2 += v * v; }
            #pragma unroll
            for (int mm = 1; mm < 16; mm <<= 1){ s1 += __shfl_xor(s1, mm, 64); s2 += __shfl_xor(s2, mm, 64); }
            if (lr == 0){
                const int row = 16 * rt + g * 4 + r;
                red1[row * 8 + wv] = s1;
                red2[row * 8 + wv] = s2;
            }
        }
    }
    __syncthreads();
    if (tid < 64){
        float S1 = 0.f, S2 = 0.f;
        #pragma unroll
        for (int w = 0; w < 8; ++w){ S1 += red1[tid * 8 + w]; S2 += red2[tid * 8 + w]; }
        const float mu = S1 * (1.0f / 512.0f);
        const float var = S2 * (1.0f / 512.0f) - mu * mu;
        stat_mu[tid] = mu;
        stat_rs[tid] = rsqrtf(var + 1e-5f);
    }
    __syncthreads();
    #pragma unroll
    for (int rt = 0; rt < 4; ++rt){
        #pragma unroll
        for (int r = 0; r < 4; ++r){
            const int row = 16 * rt + g * 4 + r;
            const float mu = stat_mu[row];
            const float rs = stat_rs[row];
            #pragma unroll
            for (int ct = 0; ct < 4; ++ct){
                const int d = nb + 16 * ct + lr;
                const float v = ((acc[rt][ct][r] - mu) * rs * gamma[d] + beta[d]) * scale;
                outp[(size_t)(r0 + row) * DIM + d] = f2bf(v);
            }
        }
    }
}

// ---------------- kernel 2: flash attention, 2 blocks/CU ----------------
// grid 512 = 8 batch * 64 pairs. Block handles 32 q-rows: rows 0-15 = q-tile t
// (light), rows 16-31 = q-tile 127-t (heavy). KB=32 kv per iter, n = 33..64 iters.
// QK split over 8 waves: 4 S-tiles (rt_,ct) x 2 K-halves (kh), partial sums in
// 2 LDS planes, combined in softmax. LDS 78.2 KB -> 2 blocks/CU (16 waves/CU).
__global__ __launch_bounds__(512, 4) void attn(
    const unsigned short* __restrict__ qb, const unsigned short* __restrict__ kb,
    const unsigned short* __restrict__ vt, const float* __restrict__ qin,
    const float* __restrict__ g_o, const float* __restrict__ b_o,
    float* __restrict__ outp)
{
    __shared__ unsigned short k_lds[2 * 32 * DIM];   // 64 KB dbuf, swizzled content
    __shared__ float s2_lds[2 * 32 * 32];            // 8 KB: 2 K-half planes, XOR swz
    __shared__ unsigned short p_lds[32 * 64];        // 4 KB: 128B rows, XOR swz
    __shared__ float m_lds[32], l_lds[32], fac_lds[32];
    // epilogue reduction arrays alias s2_lds (dead after last softmax)
    float* red1    = s2_lds;            // [32*8]
    float* red2    = red1 + 256;        // [32*8]
    float* stat_mu = red2 + 256;        // [32]
    float* stat_rs = stat_mu + 32;      // [32]

    const int tid = threadIdx.x;
    const int wv  = tid >> 6;
    const int l   = tid & 63;
    const int g   = l >> 4;
    const int lr  = l & 15;
    const int b   = blockIdx.x & 7;       // batch -> XCD (bid % 8)
    const int t   = blockIdx.x >> 3;      // 0..63 pair index
    const int q0a = 16 * t;               // light q-tile base (rows 0..15)
    const int q0b = 16 * (127 - t);       // heavy q-tile base (rows 16..31)
    const int n   = ((2047 - 16 * t) >> 5) + 1;   // kv tiles (33..64)
    const int tL  = (16 * t + 15) >> 5;           // last iter light rows active

    const int ct  = wv & 1;               // QK col tile (16 kv cols)
    const int kh  = (wv >> 1) & 1;        // K-half (256 dims)
    const int rt_ = wv >> 2;              // QK row tile: 0=light, 1=heavy

    // Q fragments: rows 16*rt_+lr, K-half kh (qf[8] = 32 VGPR)
    bf8 qf[8];
    {
        const int qglob = rt_ ? (q0b + lr) : (q0a + lr);
        const unsigned short* qr = qb + (size_t)(b * SEQ + qglob) * DIM + kh * 256 + g * 8;
        #pragma unroll
        for (int ks = 0; ks < 8; ++ks)
            qf[ks] = *reinterpret_cast<const bf8*>(qr + ks * 32);
    }

    // K staging: glds, linear dest + inverse-swizzled source (rows 4wv..4wv+3)
    auto kglds = [&](int it){
        const int bo = (it & 1) * (32 * DIM);
        #pragma unroll
        for (int i = 0; i < 4; ++i){
            const int row = 4 * wv + i;
            glds16(kb + (size_t)(b * SEQ + it * 32 + row) * DIM + ((l * 8) ^ ((row & 7) * 8)),
                   k_lds + bo + row * DIM);
        }
    };

    kglds(0);
    if (tid < 32){ m_lds[tid] = -__builtin_inff(); l_lds[tid] = 0.0f; }

    f4 acc[2][4];
    #pragma unroll
    for (int rt = 0; rt < 2; ++rt)
        #pragma unroll
        for (int cv = 0; cv < 4; ++cv)
            acc[rt][cv] = (f4){0.f, 0.f, 0.f, 0.f};
    bf8 vst[4];

    // prologue drain: K(0), Q frags, stat init
    asm volatile("s_waitcnt vmcnt(0) lgkmcnt(0)" ::: "memory");
    __builtin_amdgcn_s_barrier();
    __builtin_amdgcn_sched_barrier(0);

    // PV helper: consumes p_lds/fac (iter itp) + vst (V of iter itp)
    auto do_pv = [&](int itp){
        const bool frozen = (itp > tL);
        #pragma unroll
        for (int rt = 0; rt < 2; ++rt){
            if (rt == 0 && frozen) continue;   // light rows frozen
            float f[4];
            #pragma unroll
            for (int r = 0; r < 4; ++r) f[r] = fac_lds[16 * rt + 4 * g + r];
            #pragma unroll
            for (int cv = 0; cv < 4; ++cv)
                #pragma unroll
                for (int r = 0; r < 4; ++r)
                    acc[rt][cv][r] *= f[r];
            const int prow = 16 * rt + lr;
            const bf8 pa = *reinterpret_cast<const bf8*>(
                reinterpret_cast<const char*>(p_lds) + prow * 128 + ((g * 16) ^ ((prow & 7) << 4)));
            #pragma unroll
            for (int cv = 0; cv < 4; ++cv)
                acc[rt][cv] = __builtin_amdgcn_mfma_f32_16x16x32_bf16(pa, vst[cv], acc[rt][cv], 0, 0, 0);
        }
    };

    for (int it = 0; it < n; ++it){
        const int k0 = it * 32;
        if (it + 1 < n) kglds(it + 1);

        // ---- PV for previous iter (vst = V(it-1)) ----
        if (it > 0) do_pv(it - 1);

        // ---- V(it) loads (consumed next iter / final) ----
        #pragma unroll
        for (int cv = 0; cv < 4; ++cv)
            vst[cv] = *reinterpret_cast<const bf8*>(
                vt + (size_t)(b * DIM + 64 * wv + 16 * cv + lr) * SEQ + k0 + g * 8);

        // ---- QK(it): wave (rt_, ct, kh), K-half = 8 MFMAs ----
        if (rt_ == 1 || it <= tL){
            const char* kbuf = reinterpret_cast<const char*>(k_lds) + (it & 1) * 32768;
            const int krow  = 16 * ct + lr;
            const int rbase = krow * 1024;
            const int rx    = (krow & 7) << 4;
            f4 sa[4];
            sa[0] = (f4){0.f,0.f,0.f,0.f}; sa[1] = (f4){0.f,0.f,0.f,0.f};
            sa[2] = (f4){0.f,0.f,0.f,0.f}; sa[3] = (f4){0.f,0.f,0.f,0.f};
            #pragma unroll
            for (int ks = 0; ks < 8; ++ks){
                const bf8 bk = *reinterpret_cast<const bf8*>(
                    kbuf + rbase + (((kh * 8 + ks) * 64 + g * 16) ^ rx));
                sa[ks & 3] = __builtin_amdgcn_mfma_f32_16x16x32_bf16(qf[ks], bk, sa[ks & 3], 0, 0, 0);
            }
            const f4 s = (sa[0] + sa[1]) + (sa[2] + sa[3]);
            const int srow = 16 * rt_ + 4 * g;
            #pragma unroll
            for (int r = 0; r < 4; ++r){
                const int q = srow + r;
                s2_lds[kh * 1024 + q * 32 + ((16 * ct + lr) ^ ((q & 7) << 2))] = s[r];
            }
        }
        // b1: S partials visible; NO vmem drain (K/V loads stay in flight)
        asm volatile("s_waitcnt lgkmcnt(0)" ::: "memory");
        __builtin_amdgcn_s_barrier();
        __builtin_amdgcn_sched_barrier(0);

        // ---- softmax: rows 0..31, 8 threads/row, 4 cols each ----
        if (tid < 256){
            const int row = tid >> 3;
            const int cp  = tid & 7;
            if (row >= 16 || it <= tL){
                const int swz = (row & 7) << 2;
                const f4 x0 = *reinterpret_cast<const f4*>(&s2_lds[row * 32 + ((4 * cp) ^ swz)]);
                const f4 x1 = *reinterpret_cast<const f4*>(&s2_lds[1024 + row * 32 + ((4 * cp) ^ swz)]);
                float av[4] = {x0[0] + x1[0], x0[1] + x1[1], x0[2] + x1[2], x0[3] + x1[3]};
                const int qrow = (row < 16) ? (q0a + row) : (q0b + row - 16);
                #pragma unroll
                for (int jj = 0; jj < 4; ++jj)
                    if (k0 + 4 * cp + jj > qrow) av[jj] = -1e30f;
                float pm = fmaxf(fmaxf(av[0], av[1]), fmaxf(av[2], av[3]));
                #pragma unroll
                for (int mm = 1; mm < 8; mm <<= 1) pm = fmaxf(pm, __shfl_xor(pm, mm, 64));
                const float mo = m_lds[row];
                const float mn = fmaxf(mo, pm);
                const float e0 = __expf(av[0] - mn), e1 = __expf(av[1] - mn);
                const float e2 = __expf(av[2] - mn), e3 = __expf(av[3] - mn);
                float ts = e0 + e1 + e2 + e3;
                #pragma unroll
                for (int mm = 1; mm < 8; mm <<= 1) ts += __shfl_xor(ts, mm, 64);
                if (cp == 0){
                    const float fc = __expf(mo - mn);
                    m_lds[row] = mn; fac_lds[row] = fc;
                    l_lds[row] = l_lds[row] * fc + ts;
                }
                uint2 pk;
                pk.x = (unsigned int)f2bf(e0) | ((unsigned int)f2bf(e1) << 16);
                pk.y = (unsigned int)f2bf(e2) | ((unsigned int)f2bf(e3) << 16);
                *reinterpret_cast<uint2*>(reinterpret_cast<char*>(p_lds) +
                    row * 128 + ((cp * 8) ^ ((row & 7) << 4))) = pk;
            }
        }
        // b2: P/fac visible AND K(it+1) landed (4 V loads stay in flight)
        asm volatile("s_waitcnt vmcnt(4)" ::: "memory");
        asm volatile("s_waitcnt lgkmcnt(0)" ::: "memory");
        __builtin_amdgcn_s_barrier();
        __builtin_amdgcn_sched_barrier(0);
    }

    // final PV (softmax/V of iter n-1)
    asm volatile("s_waitcnt vmcnt(0)" ::: "memory");
    do_pv(n - 1);

    // ---- finalize: /l, +residual, LN, store (32 rows) ----
    float li[2][4];
    #pragma unroll
    for (int rt = 0; rt < 2; ++rt)
        #pragma unroll
        for (int r = 0; r < 4; ++r)
            li[rt][r] = 1.0f / l_lds[16 * rt + 4 * g + r];
    #pragma unroll
    for (int rt = 0; rt < 2; ++rt){
        #pragma unroll
        for (int cv = 0; cv < 4; ++cv){
            #pragma unroll
            for (int r = 0; r < 4; ++r){
                const int row = 16 * rt + 4 * g + r;
                const int qglob = (row < 16) ? (q0a + row) : (q0b + row - 16);
                const int d = 64 * wv + 16 * cv + lr;
                acc[rt][cv][r] = acc[rt][cv][r] * li[rt][r]
                               + qin[(size_t)(b * SEQ + qglob) * DIM + d];
            }
        }
    }
    // all waves passed b2(n-1) barrier -> s2_lds is dead; safe to reuse as red1/red2
    #pragma unroll
    for (int rt = 0; rt < 2; ++rt){
        #pragma unroll
        for (int r = 0; r < 4; ++r){
            float s1 = 0.f, s2 = 0.f;
            #pragma unroll
            for (int cv = 0; cv < 4; ++cv){ const float v = acc[rt][cv][r]; s1 += v; s2 += v * v; }
            #pragma unroll
            for (int mm = 1; mm < 16; mm <<= 1){ s1 += __shfl_xor(s1, mm, 64); s2 += __shfl_xor(s2, mm, 64); }
            if (lr == 0){
                const int row = 16 * rt + 4 * g + r;
                red1[row * 8 + wv] = s1;
                red2[row * 8 + wv] = s2;
            }
        }
    }
    __syncthreads();
    if (tid < 32){
        float S1 = 0.f, S2 = 0.f;
        #pragma unroll
        for (int w = 0; w < 8; ++w){ S1 += red1[tid * 8 + w]; S2 += red2[tid * 8 + w]; }
        const float mu = S1 * (1.0f / 512.0f);
        const float var = S2 * (1.0f / 512.0f) - mu * mu;
        stat_mu[tid] = mu;
        stat_rs[tid] = rsqrtf(var + 1e-5f);
    }
    __syncthreads();
    #pragma unroll
    for (int rt = 0; rt < 2; ++rt){
        #pragma unroll
        for (int r = 0; r < 4; ++r){
            const int row = 16 * rt + 4 * g + r;
            const int qglob = (row < 16) ? (q0a + row) : (q0b + row - 16);
            const float mu = stat_mu[row];
            const float rs = stat_rs[row];
            #pragma unroll
            for (int cv = 0; cv < 4; ++cv){
                const int d = 64 * wv + 16 * cv + lr;
                outp[(size_t)(b * SEQ + qglob) * DIM + d] =
                    (acc[rt][cv][r] - mu) * rs * g_o[d] + b_o[d];
            }
        }
    }
}

extern "C" void kernel_launch(void* const* d_in, const int* in_sizes, int n_in,
                              void* d_out, int out_size, void* d_ws, size_t ws_size,
                              hipStream_t stream)
{
    (void)in_sizes; (void)n_in; (void)out_size; (void)ws_size;
    const float* vals = (const float*)d_in[0];
    const float* keys = (const float*)d_in[1];
    const float* ques = (const float*)d_in[2];
    const float* Wv   = (const float*)d_in[5];
    const float* Wk   = (const float*)d_in[6];
    const float* Wq   = (const float*)d_in[7];
    const float* ln_k_g = (const float*)d_in[8];
    const float* ln_k_b = (const float*)d_in[9];
    const float* ln_q_g = (const float*)d_in[10];
    const float* ln_q_b = (const float*)d_in[11];
    const float* ln_o_g = (const float*)d_in[12];
    const float* ln_o_b = (const float*)d_in[13];
    float* outp = (float*)d_out;

    char* ws = (char*)d_ws;
    unsigned short* qbuf = (unsigned short*)(ws);
    unsigned short* kbuf = (unsigned short*)(ws + (size_t)16 * 1024 * 1024);
    unsigned short* vt   = (unsigned short*)(ws + (size_t)32 * 1024 * 1024);
    unsigned short* Wt   = (unsigned short*)(ws + (size_t)48 * 1024 * 1024);

    prep_w<<<dim3(1024, 3), 256, 0, stream>>>(Wv, Wk, Wq, Wt);

    gemm3<<<768, 512, 0, stream>>>(vals, keys, ques, Wt,
                                   ln_k_g, ln_k_b, ln_q_g, ln_q_b,
                                   vt, kbuf, qbuf);

    attn<<<512, 512, 0, stream>>>(qbuf, kbuf, vt, ques, ln_o_g, ln_o_b, outp);
}

// Round 2
// 193.987 us; speedup vs baseline: 1.8046x; 1.8046x over previous
//
#include <hip/hip_runtime.h>
#include <cstdint>

typedef short bf8 __attribute__((ext_vector_type(8)));
typedef float f4 __attribute__((ext_vector_type(4)));

#define SEQ 2048
#define DIM 512
#define NMAT (512*512)
#define SCQ 0.04419417382415922f

__device__ inline unsigned short f2bf(float f){
    unsigned int u = __builtin_bit_cast(unsigned int, f);
    u = (u + 0x7FFFu + ((u >> 16) & 1u)) >> 16;
    return (unsigned short)u;
}

__device__ __forceinline__ void glds16(const unsigned short* gsrc, const unsigned short* ldst){
    __builtin_amdgcn_global_load_lds(
        (const __attribute__((address_space(1))) unsigned int*)gsrc,
        (__attribute__((address_space(3))) unsigned int*)ldst, 16, 0, 0);
}

// ---------------- kernel 0: W (f32 [k][n]) -> Wt (bf16 [n][k]) ----------------
__global__ void prep_w(const float* __restrict__ Wv, const float* __restrict__ Wk,
                       const float* __restrict__ Wq, unsigned short* __restrict__ Wt)
{
    const int m = blockIdx.y;
    const float* W = (m == 0) ? Wv : ((m == 1) ? Wk : Wq);
    const int o = blockIdx.x * 256 + threadIdx.x;
    const int n = o >> 9;
    const int k = o & 511;
    Wt[m * NMAT + o] = f2bf(W[k * 512 + n]);
}

// ---------------- kernel 1: fused 3x GEMM (+LN / +transpose epilogue) ----------------
__global__ __launch_bounds__(512, 1) void gemm3(
    const float* __restrict__ vals, const float* __restrict__ keys, const float* __restrict__ ques,
    const unsigned short* __restrict__ Wt,
    const float* __restrict__ kg, const float* __restrict__ kbe,
    const float* __restrict__ qg, const float* __restrict__ qbe,
    unsigned short* __restrict__ vt, unsigned short* __restrict__ kbuf, unsigned short* __restrict__ qbuf)
{
    __shared__ unsigned short a_lds[64 * DIM];   // 64 KB, XOR-swizzled rows
    float* red1    = (float*)a_lds;
    float* red2    = red1 + 512;
    float* stat_mu = red2 + 512;
    float* stat_rs = stat_mu + 64;

    const int tid = threadIdx.x;
    const int wv  = tid >> 6;
    const int l   = tid & 63;
    const int g   = l >> 4;
    const int lr  = l & 15;
    const int gid = blockIdx.x;
    const int m   = gid >> 8;            // 0=v, 1=k, 2=q
    const int r0  = (gid & 255) * 64;
    const float* X = (m == 0) ? vals : ((m == 1) ? keys : ques);
    const unsigned short* W = Wt + m * NMAT;

    {
        const int row = tid >> 3;
        const int cb  = (tid & 7) * 4;
        const float* xr = X + (size_t)(r0 + row) * DIM;
        #pragma unroll
        for (int i = 0; i < 16; ++i){
            const int col = cb + i * 32;
            const float4 v = *reinterpret_cast<const float4*>(xr + col);
            ushort4 h;
            h.x = f2bf(v.x); h.y = f2bf(v.y); h.z = f2bf(v.z); h.w = f2bf(v.w);
            const int byte = ((row * DIM + col) * 2) ^ ((row & 7) << 4);
            *reinterpret_cast<ushort4*>(reinterpret_cast<char*>(a_lds) + byte) = h;
        }
    }
    __syncthreads();

    f4 acc[4][4];
    #pragma unroll
    for (int i = 0; i < 4; ++i)
        #pragma unroll
        for (int j = 0; j < 4; ++j)
            acc[i][j] = (f4){0.f, 0.f, 0.f, 0.f};

    const int nb = wv * 64;
    #pragma unroll 4
    for (int ks = 0; ks < 16; ++ks){
        const int kof = ks * 32 + g * 8;
        bf8 af[4], bfr[4];
        #pragma unroll
        for (int rt = 0; rt < 4; ++rt){
            const int row = 16 * rt + lr;
            const int byte = ((row * DIM + kof) * 2) ^ ((row & 7) << 4);
            af[rt] = *reinterpret_cast<const bf8*>(reinterpret_cast<const char*>(a_lds) + byte);
        }
        #pragma unroll
        for (int ct = 0; ct < 4; ++ct)
            bfr[ct] = *reinterpret_cast<const bf8*>(W + (size_t)(nb + 16 * ct + lr) * DIM + kof);
        #pragma unroll
        for (int rt = 0; rt < 4; ++rt)
            #pragma unroll
            for (int ct = 0; ct < 4; ++ct)
                acc[rt][ct] = __builtin_amdgcn_mfma_f32_16x16x32_bf16(af[rt], bfr[ct], acc[rt][ct], 0, 0, 0);
    }

    if (m == 0){
        __syncthreads();
        #pragma unroll
        for (int rt = 0; rt < 4; ++rt)
            #pragma unroll
            for (int r = 0; r < 4; ++r){
                const int row = 16 * rt + g * 4 + r;
                #pragma unroll
                for (int ct = 0; ct < 4; ++ct){
                    const int d = nb + 16 * ct + lr;
                    const int byte = (d * 128 + row * 2) ^ ((d & 7) << 4);
                    *reinterpret_cast<unsigned short*>(reinterpret_cast<char*>(a_lds) + byte) = f2bf(acc[rt][ct][r]);
                }
            }
        __syncthreads();
        const int bb = r0 >> 11;
        const int s0 = r0 & 2047;
        #pragma unroll
        for (int pq = 0; pq < 4; ++pq){
            const int d  = pq * 128 + (tid >> 2);
            const int sc = (tid & 3) * 16;
            const int base = d * 128 + sc * 2;
            const int sw = (d & 7) << 4;
            const bf8 x0 = *reinterpret_cast<const bf8*>(reinterpret_cast<const char*>(a_lds) + (base ^ sw));
            const bf8 x1 = *reinterpret_cast<const bf8*>(reinterpret_cast<const char*>(a_lds) + ((base + 16) ^ sw));
            unsigned short* dst = vt + (size_t)(bb * 512 + d) * SEQ + s0 + sc;
            *reinterpret_cast<bf8*>(dst)     = x0;
            *reinterpret_cast<bf8*>(dst + 8) = x1;
        }
        return;
    }

    const float* gamma = (m == 1) ? kg  : qg;
    const float* beta  = (m == 1) ? kbe : qbe;
    const float scale  = (m == 1) ? 1.0f : SCQ;
    unsigned short* outp = (m == 1) ? kbuf : qbuf;

    __syncthreads();
    #pragma unroll
    for (int rt = 0; rt < 4; ++rt){
        #pragma unroll
        for (int r = 0; r < 4; ++r){
            float s1 = 0.f, s2 = 0.f;
            #pragma unroll
            for (int ct = 0; ct < 4; ++ct){ const float v = acc[rt][ct][r]; s1 += v; s2 += v * v; }
            #pragma unroll
            for (int mm = 1; mm < 16; mm <<= 1){ s1 += __shfl_xor(s1, mm, 64); s2 += __shfl_xor(s2, mm, 64); }
            if (lr == 0){
                const int row = 16 * rt + g * 4 + r;
                red1[row * 8 + wv] = s1;
                red2[row * 8 + wv] = s2;
            }
        }
    }
    __syncthreads();
    if (tid < 64){
        float S1 = 0.f, S2 = 0.f;
        #pragma unroll
        for (int w = 0; w < 8; ++w){ S1 += red1[tid * 8 + w]; S2 += red2[tid * 8 + w]; }
        const float mu = S1 * (1.0f / 512.0f);
        const float var = S2 * (1.0f / 512.0f) - mu * mu;
        stat_mu[tid] = mu;
        stat_rs[tid] = rsqrtf(var + 1e-5f);
    }
    __syncthreads();
    #pragma unroll
    for (int rt = 0; rt < 4; ++rt){
        #pragma unroll
        for (int r = 0; r < 4; ++r){
            const int row = 16 * rt + g * 4 + r;
            const float mu = stat_mu[row];
            const float rs = stat_rs[row];
            #pragma unroll
            for (int ct = 0; ct < 4; ++ct){
                const int d = nb + 16 * ct + lr;
                const float v = ((acc[rt][ct][r] - mu) * rs * gamma[d] + beta[d]) * scale;
                outp[(size_t)(r0 + row) * DIM + d] = f2bf(v);
            }
        }
    }
}

// ---------------- kernel 2: flash attention, KB=64 per iteration ----------------
// grid 256 = 8 batch * 32 p. Rows 0-31 = qt=p (light), rows 32-63 = qt=63-p.
// Each iteration j processes kv pair (2j, 2j+1) = 64 kv columns; n2 = 17..32 iters.
// K via global_load_lds into ring-4 of 32-row buffers (128 KB); prefetch 2 tiles
// ahead; b1 = lgkmcnt(0) only, b2 = vmcnt(8) (drains the 8 prefetch glds, the 8
// V loads stay in flight across b2 into next iter's PV).
__global__ __launch_bounds__(512, 2) void attn(
    const unsigned short* __restrict__ qb, const unsigned short* __restrict__ kb,
    const unsigned short* __restrict__ vt, const float* __restrict__ qin,
    const float* __restrict__ g_o, const float* __restrict__ b_o,
    float* __restrict__ outp)
{
    __shared__ unsigned short k_lds[4 * 32 * DIM];   // 128 KB ring-4, swizzled content
    __shared__ float s_lds[64][68];                  // 17.4 KB: 64x64 S + pad (f4-aligned)
    __shared__ unsigned short p_lds[64 * 64];        // 8 KB: 128B rows, XOR swz, fully used
    __shared__ float m_lds[64], l_lds[64], fac_lds[64];
    // epilogue reduction arrays alias s_lds (dead after last softmax)
    float* red1    = &s_lds[0][0];
    float* red2    = red1 + 512;
    float* stat_mu = red2 + 512;
    float* stat_rs = stat_mu + 64;

    const int tid = threadIdx.x;
    const int wv  = tid >> 6;
    const int l   = tid & 63;
    const int g   = l >> 4;
    const int lr  = l & 15;
    const int b   = blockIdx.x & 7;
    const int p   = blockIdx.x >> 3;      // 0..31
    const int q0a = 32 * p;               // rows 0..31  (light)
    const int q0b = 32 * (63 - p);        // rows 32..63 (heavy)
    const int n2  = (65 - p) >> 1;        // kv pairs (17..32); odd tail tile is
                                          // fully causal-masked -> contributes 0
    const int jL  = p >> 1;               // last pair with light rows active

    const int ct  = wv & 1;               // QK col tile (16 cols within 32-tile)
    const int rt_ = wv >> 1;              // QK row tile (16 rows), 0..3

    // Q fragments: rows 16*rt_+lr, full K=512 (qf[16] = 64 VGPR)
    bf8 qf[16];
    {
        const int row = 16 * rt_ + lr;
        const int qglob = (row < 32) ? (q0a + row) : (q0b + row - 32);
        const unsigned short* qr = qb + (size_t)(b * SEQ + qglob) * DIM + g * 8;
        #pragma unroll
        for (int ks = 0; ks < 16; ++ks)
            qf[ks] = *reinterpret_cast<const bf8*>(qr + ks * 32);
    }

    // K staging: glds, linear dest + inverse-swizzled source (rows 4wv..4wv+3)
    auto kglds = [&](int t){
        const int bo = (t & 3) * (32 * DIM);
        #pragma unroll
        for (int i = 0; i < 4; ++i){
            const int row = 4 * wv + i;
            glds16(kb + (size_t)(b * SEQ + t * 32 + row) * DIM + ((l * 8) ^ ((row & 7) * 8)),
                   k_lds + bo + row * DIM);
        }
    };

    kglds(0);
    kglds(1);
    if (tid < 64){ m_lds[tid] = -__builtin_inff(); l_lds[tid] = 0.0f; }

    f4 acc[4][4];
    #pragma unroll
    for (int rt = 0; rt < 4; ++rt)
        #pragma unroll
        for (int cv = 0; cv < 4; ++cv)
            acc[rt][cv] = (f4){0.f, 0.f, 0.f, 0.f};
    bf8 vst[8];   // [cv][ks]: V fragments for current 64-kv chunk

    // prologue drain: K(0), K(1), Q frags
    asm volatile("s_waitcnt vmcnt(0)" ::: "memory");
    __builtin_amdgcn_s_barrier();
    __builtin_amdgcn_sched_barrier(0);

    // PV helper: consumes p_lds/fac (pair jp) + vst (V of pair jp)
    auto do_pv = [&](int jp){
        const bool frozen = (jp > jL);
        #pragma unroll
        for (int rt = 0; rt < 4; ++rt){
            if (rt < 2 && frozen) continue;    // light rows frozen
            float f[4];
            #pragma unroll
            for (int r = 0; r < 4; ++r) f[r] = fac_lds[16 * rt + 4 * g + r];
            #pragma unroll
            for (int cv = 0; cv < 4; ++cv)
                #pragma unroll
                for (int r = 0; r < 4; ++r)
                    acc[rt][cv][r] *= f[r];
            const int prow = 16 * rt + lr;
            const int sw = (prow & 7) << 4;
            const bf8 pa0 = *reinterpret_cast<const bf8*>(
                reinterpret_cast<const char*>(p_lds) + prow * 128 + ((g * 16) ^ sw));
            const bf8 pa1 = *reinterpret_cast<const bf8*>(
                reinterpret_cast<const char*>(p_lds) + prow * 128 + ((64 + g * 16) ^ sw));
            #pragma unroll
            for (int cv = 0; cv < 4; ++cv){
                acc[rt][cv] = __builtin_amdgcn_mfma_f32_16x16x32_bf16(pa0, vst[2 * cv],     acc[rt][cv], 0, 0, 0);
                acc[rt][cv] = __builtin_amdgcn_mfma_f32_16x16x32_bf16(pa1, vst[2 * cv + 1], acc[rt][cv], 0, 0, 0);
            }
        }
    };

    for (int j = 0; j < n2; ++j){
        const int k0 = 64 * j;
        const int tp = 2 * j + 2;
        if (tp     < 2 * n2) kglds(tp);
        if (tp + 1 < 2 * n2) kglds(tp + 1);

        // ---- PV for previous pair (vst = V(j-1), counted vmcnt inserted by compiler) ----
        if (j > 0) do_pv(j - 1);

        // ---- V(j) loads: 64 kv cols (consumed next iter / final) ----
        #pragma unroll
        for (int cv = 0; cv < 4; ++cv)
            #pragma unroll
            for (int ks = 0; ks < 2; ++ks)
                vst[2 * cv + ks] = *reinterpret_cast<const bf8*>(
                    vt + (size_t)(b * DIM + 64 * wv + 16 * cv + lr) * SEQ + k0 + 32 * ks + g * 8);

        // ---- QK(j): wave (rt_, ct), two 32-col halves, full K=512 each ----
        if (rt_ >= 2 || j <= jL){
            const int krow  = 16 * ct + lr;
            const int rbase = krow * 1024;
            const int rx    = (krow & 7) << 4;
            #pragma unroll
            for (int h = 0; h < 2; ++h){
                const char* kbuf = reinterpret_cast<const char*>(k_lds) + ((2 * j + h) & 3) * 32768;
                f4 sa[4];
                sa[0] = (f4){0.f,0.f,0.f,0.f}; sa[1] = (f4){0.f,0.f,0.f,0.f};
                sa[2] = (f4){0.f,0.f,0.f,0.f}; sa[3] = (f4){0.f,0.f,0.f,0.f};
                #pragma unroll
                for (int ks = 0; ks < 16; ++ks){
                    const bf8 bk = *reinterpret_cast<const bf8*>(
                        kbuf + rbase + ((ks * 64 + g * 16) ^ rx));
                    sa[ks & 3] = __builtin_amdgcn_mfma_f32_16x16x32_bf16(qf[ks], bk, sa[ks & 3], 0, 0, 0);
                }
                const f4 s = (sa[0] + sa[1]) + (sa[2] + sa[3]);
                const int srow = 16 * rt_ + 4 * g;
                #pragma unroll
                for (int r = 0; r < 4; ++r)
                    s_lds[srow + r][32 * h + 16 * ct + lr] = s[r];
            }
        }
        // b1: S visible; NO vmem drain (K/V loads stay in flight)
        asm volatile("s_waitcnt lgkmcnt(0)" ::: "memory");
        __builtin_amdgcn_s_barrier();
        __builtin_amdgcn_sched_barrier(0);

        // ---- softmax: row = tid>>3, 8 cols/thread over 64 kv cols ----
        {
            const int row = tid >> 3;
            const int cp  = tid & 7;
            if (row >= 32 || j <= jL){
                const float4 x0 = *reinterpret_cast<const float4*>(&s_lds[row][8 * cp]);
                const float4 x1 = *reinterpret_cast<const float4*>(&s_lds[row][8 * cp + 4]);
                float av[8] = {x0.x, x0.y, x0.z, x0.w, x1.x, x1.y, x1.z, x1.w};
                const int qrow = (row < 32) ? (q0a + row) : (q0b + row - 32);
                const int kc = k0 + 8 * cp;
                #pragma unroll
                for (int jj = 0; jj < 8; ++jj)
                    if (kc + jj > qrow) av[jj] = -1e30f;
                float pm = fmaxf(fmaxf(fmaxf(av[0], av[1]), fmaxf(av[2], av[3])),
                                 fmaxf(fmaxf(av[4], av[5]), fmaxf(av[6], av[7])));
                #pragma unroll
                for (int mm = 1; mm < 8; mm <<= 1) pm = fmaxf(pm, __shfl_xor(pm, mm, 64));
                const float mo = m_lds[row];
                const float mn = fmaxf(mo, pm);
                float e[8];
                #pragma unroll
                for (int jj = 0; jj < 8; ++jj) e[jj] = __expf(av[jj] - mn);
                float ts = ((e[0] + e[1]) + (e[2] + e[3])) + ((e[4] + e[5]) + (e[6] + e[7]));
                #pragma unroll
                for (int mm = 1; mm < 8; mm <<= 1) ts += __shfl_xor(ts, mm, 64);
                if (cp == 0){
                    const float fc = __expf(mo - mn);
                    m_lds[row] = mn; fac_lds[row] = fc;
                    l_lds[row] = l_lds[row] * fc + ts;
                }
                uint4 pk;
                pk.x = (unsigned int)f2bf(e[0]) | ((unsigned int)f2bf(e[1]) << 16);
                pk.y = (unsigned int)f2bf(e[2]) | ((unsigned int)f2bf(e[3]) << 16);
                pk.z = (unsigned int)f2bf(e[4]) | ((unsigned int)f2bf(e[5]) << 16);
                pk.w = (unsigned int)f2bf(e[6]) | ((unsigned int)f2bf(e[7]) << 16);
                *reinterpret_cast<uint4*>(reinterpret_cast<char*>(p_lds) +
                    row * 128 + ((cp * 16) ^ ((row & 7) << 4))) = pk;
            }
        }
        // b2: P/fac visible AND prefetched K landed (8 glds drained; 8 V loads in flight)
        asm volatile("s_waitcnt vmcnt(8)" ::: "memory");
        asm volatile("s_waitcnt lgkmcnt(0)" ::: "memory");
        __builtin_amdgcn_s_barrier();
        __builtin_amdgcn_sched_barrier(0);
    }

    // final PV (softmax/V of pair n2-1)
    asm volatile("s_waitcnt vmcnt(0)" ::: "memory");
    do_pv(n2 - 1);

    // ---- finalize: /l, +residual, LN, store (64 rows) ----
    float li[4][4];
    #pragma unroll
    for (int rt = 0; rt < 4; ++rt)
        #pragma unroll
        for (int r = 0; r < 4; ++r)
            li[rt][r] = 1.0f / l_lds[16 * rt + 4 * g + r];
    #pragma unroll
    for (int rt = 0; rt < 4; ++rt){
        #pragma unroll
        for (int cv = 0; cv < 4; ++cv){
            #pragma unroll
            for (int r = 0; r < 4; ++r){
                const int row = 16 * rt + 4 * g + r;
                const int qglob = (row < 32) ? (q0a + row) : (q0b + row - 32);
                const int d = 64 * wv + 16 * cv + lr;
                acc[rt][cv][r] = acc[rt][cv][r] * li[rt][r]
                               + qin[(size_t)(b * SEQ + qglob) * DIM + d];
            }
        }
    }
    // all waves passed b2(n2-1) -> s_lds dead; safe to reuse as red1/red2/stat
    #pragma unroll
    for (int rt = 0; rt < 4; ++rt){
        #pragma unroll
        for (int r = 0; r < 4; ++r){
            float s1 = 0.f, s2 = 0.f;
            #pragma unroll
            for (int cv = 0; cv < 4; ++cv){ const float v = acc[rt][cv][r]; s1 += v; s2 += v * v; }
            #pragma unroll
            for (int mm = 1; mm < 16; mm <<= 1){ s1 += __shfl_xor(s1, mm, 64); s2 += __shfl_xor(s2, mm, 64); }
            if (lr == 0){
                const int row = 16 * rt + 4 * g + r;
                red1[row * 8 + wv] = s1;
                red2[row * 8 + wv] = s2;
            }
        }
    }
    __syncthreads();
    if (tid < 64){
        float S1 = 0.f, S2 = 0.f;
        #pragma unroll
        for (int w = 0; w < 8; ++w){ S1 += red1[tid * 8 + w]; S2 += red2[tid * 8 + w]; }
        const float mu = S1 * (1.0f / 512.0f);
        const float var = S2 * (1.0f / 512.0f) - mu * mu;
        stat_mu[tid] = mu;
        stat_rs[tid] = rsqrtf(var + 1e-5f);
    }
    __syncthreads();
    #pragma unroll
    for (int rt = 0; rt < 4; ++rt){
        #pragma unroll
        for (int r = 0; r < 4; ++r){
            const int row = 16 * rt + 4 * g + r;
            const int qglob = (row < 32) ? (q0a + row) : (q0b + row - 32);
            const float mu = stat_mu[row];
            const float rs = stat_rs[row];
            #pragma unroll
            for (int cv = 0; cv < 4; ++cv){
                const int d = 64 * wv + 16 * cv + lr;
                outp[(size_t)(b * SEQ + qglob) * DIM + d] =
                    (acc[rt][cv][r] - mu) * rs * g_o[d] + b_o[d];
            }
        }
    }
}

extern "C" void kernel_launch(void* const* d_in, const int* in_sizes, int n_in,
                              void* d_out, int out_size, void* d_ws, size_t ws_size,
                              hipStream_t stream)
{
    (void)in_sizes; (void)n_in; (void)out_size; (void)ws_size;
    const float* vals = (const float*)d_in[0];
    const float* keys = (const float*)d_in[1];
    const float* ques = (const float*)d_in[2];
    const float* Wv   = (const float*)d_in[5];
    const float* Wk   = (const float*)d_in[6];
    const float* Wq   = (const float*)d_in[7];
    const float* ln_k_g = (const float*)d_in[8];
    const float* ln_k_b = (const float*)d_in[9];
    const float* ln_q_g = (const float*)d_in[10];
    const float* ln_q_b = (const float*)d_in[11];
    const float* ln_o_g = (const float*)d_in[12];
    const float* ln_o_b = (const float*)d_in[13];
    float* outp = (float*)d_out;

    char* ws = (char*)d_ws;
    unsigned short* qbuf = (unsigned short*)(ws);
    unsigned short* kbuf = (unsigned short*)(ws + (size_t)16 * 1024 * 1024);
    unsigned short* vt   = (unsigned short*)(ws + (size_t)32 * 1024 * 1024);
    unsigned short* Wt   = (unsigned short*)(ws + (size_t)48 * 1024 * 1024);

    prep_w<<<dim3(1024, 3), 256, 0, stream>>>(Wv, Wk, Wq, Wt);

    gemm3<<<768, 512, 0, stream>>>(vals, keys, ques, Wt,
                                   ln_k_g, ln_k_b, ln_q_g, ln_q_b,
                                   vt, kbuf, qbuf);

    attn<<<256, 512, 0, stream>>>(qbuf, kbuf, vt, ques, ln_o_g, ln_o_b, outp);
}